// Round 11
// baseline (134.365 us; speedup 1.0000x reference)
//
#include <hip/hip_runtime.h>
#include <hip/hip_bf16.h>

namespace {

constexpr int kHW = 36864;  // 192*192
constexpr int kRepackBlocks = 2304;  // 144 px-tiles x 8 ks x 2 b
constexpr int kGemmBlocks = 1152;    // 576 tiles x 2 b

typedef __attribute__((ext_vector_type(8))) short bf16x8;
typedef __attribute__((ext_vector_type(4))) float f32x4;

__device__ __forceinline__ unsigned short f2bf(float x) {
  return __builtin_bit_cast(unsigned short, __float2bfloat16(x));
}
__device__ __forceinline__ float bf2f(unsigned short u) {
  return __builtin_bit_cast(float, (unsigned int)u << 16);
}

__device__ __forceinline__ float wave_sum(float v) {
#pragma unroll
  for (int off = 32; off; off >>= 1) v += __shfl_xor(v, off, 64);
  return v;
}

// ---------------------------------------------------------------------------
// K1: repack mask_out -> frag-ready bf16 moT, plus prep (zero acc, gather K).
// (unchanged from R9; repack proven < fill time)
// ---------------------------------------------------------------------------
__global__ __launch_bounds__(256, 4) void repack_prep_kernel(
    const float* __restrict__ mask_out,
    const float* __restrict__ k0, const float* __restrict__ k1,
    const float* __restrict__ k2, const float* __restrict__ k3,
    const float* __restrict__ k4,
    const int* __restrict__ q0, const int* __restrict__ q1,
    const int* __restrict__ q2, const int* __restrict__ q3,
    const int* __restrict__ q4,
    unsigned short* __restrict__ moT, unsigned short* __restrict__ kbf,
    float* __restrict__ acc) {
  const int bid = blockIdx.x;
  if (bid >= kRepackBlocks) {
    const int pid = bid - kRepackBlocks;
    if (pid == 0) {
      for (int i = threadIdx.x; i < 482; i += 256) acc[i] = 0.f;
      return;
    }
    const int idx = pid - 1;  // 0..159
    const int b = idx / 80;
    const int row = idx - b * 80;
    if (threadIdx.x >= 128) return;
    const int l = row >> 4, p = row & 15;
    const float* kb[5] = {k0, k1, k2, k3, k4};
    const int* pb[5] = {q0, q1, q2, q3, q4};
    const int bg2[5] = {b * 1600, b * 1296, b * 576, b * 256, b * 144};
    const int pos = pb[l][b * 16 + p];
    const int ch = threadIdx.x * 2;
    const float2 kv =
        *(const float2*)(kb[l] + (size_t)(bg2[l] + pos) * 256 + ch);
    *(unsigned int*)&kbf[((size_t)b * 80 + row) * 256 + ch] =
        (unsigned int)f2bf(kv.x) | ((unsigned int)f2bf(kv.y) << 16);
    return;
  }

  const int b = bid / 1152;
  const int rem = bid - b * 1152;
  const int ks = rem / 144;
  const int pxt = rem - ks * 144;  // 256-px tile index
  const int lane = threadIdx.x & 63;
  const int wv = threadIdx.x >> 6;

  __shared__ unsigned short ldsC[32][524];  // 33.5 KB, row stride 1048 B

  const float* __restrict__ src =
      mask_out + (size_t)b * 256 * kHW + (size_t)ks * 32 * kHW + pxt * 256;

#pragma unroll
  for (int i = 0; i < 8; ++i) {
    const int ch = wv * 8 + i;
    const float4 v = *(const float4*)&src[(size_t)ch * kHW + lane * 4];
    uint2 pk;
    pk.x = (unsigned int)f2bf(v.x) | ((unsigned int)f2bf(v.y) << 16);
    pk.y = (unsigned int)f2bf(v.z) | ((unsigned int)f2bf(v.w) << 16);
    *(uint2*)&ldsC[ch][lane * 4] = pk;
  }
  __syncthreads();

  const int px16 = lane & 15, kh = lane >> 4;
  unsigned short* __restrict__ dstbase =
      moT + (((size_t)b * 2304 + pxt * 16) * 8 + ks) * 512 + (size_t)lane * 8;
#pragma unroll
  for (int f = 0; f < 4; ++f) {
    const int pxblk = (threadIdx.x >> 6) * 4 + f;  // 0..15 local
    const int px = pxblk * 16 + px16;
    bf16x8 frag;
#pragma unroll
    for (int j = 0; j < 8; ++j) frag[j] = (short)ldsC[kh * 8 + j][px];
    *(bf16x8*)(dstbase + (size_t)pxblk * 4096) = frag;
  }
}

// ---------------------------------------------------------------------------
// DIAGNOSTIC 1: loads + MFMA only. Results kept alive via asm; no stores.
// ---------------------------------------------------------------------------
__global__ __launch_bounds__(256, 4) void gemm_only_diag(
    const unsigned short* __restrict__ moT,
    const unsigned short* __restrict__ kbf) {
  const int bid = blockIdx.x;
  const int b = bid / 576;
  const int tile = bid - b * 576;
  const int lane = threadIdx.x & 63;
  const int wv = threadIdx.x >> 6;
  const int px16 = lane & 15;
  const int hi8 = (lane >> 4) * 8;
  const int pxblk = tile * 4 + wv;

  const unsigned short* __restrict__ bsrc =
      moT + ((size_t)(b * 2304 + pxblk) * 8) * 512 + (size_t)lane * 8;
  bf16x8 bfr[8];
#pragma unroll
  for (int ks = 0; ks < 8; ++ks)
    bfr[ks] = *(const bf16x8*)(bsrc + (size_t)ks * 512);

  const unsigned short* __restrict__ ka =
      kbf + ((size_t)b * 80 + px16) * 256 + hi8;

  f32x4 a5[5];
#pragma unroll
  for (int mt = 0; mt < 5; ++mt) a5[mt] = (f32x4){0.f, 0.f, 0.f, 0.f};

#pragma unroll
  for (int ks = 0; ks < 8; ++ks) {
#pragma unroll
    for (int mt = 0; mt < 5; ++mt) {
      const bf16x8 af = *(const bf16x8*)(ka + mt * 4096 + ks * 32);
      a5[mt] = __builtin_amdgcn_mfma_f32_16x16x32_bf16(af, bfr[ks], a5[mt],
                                                       0, 0, 0);
    }
  }
  // keep results live without memory side effects (rule #17)
#pragma unroll
  for (int mt = 0; mt < 5; ++mt)
#pragma unroll
    for (int j = 0; j < 4; ++j) asm volatile("" ::"v"(a5[mt][j]));
}

// ---------------------------------------------------------------------------
// DIAGNOSTIC 2: the dice epilogue alone, with a fabricated pred. Atomics go
// to a scratch region of acc (never read by finalize).
// ---------------------------------------------------------------------------
__global__ __launch_bounds__(256, 4) void epi_only_diag(
    const float* __restrict__ mask_targets, float* __restrict__ acc) {
  __shared__ float bred[4][240];
  const int bid = blockIdx.x;
  const int b = bid / 576;
  const int tile = bid - b * 576;
  const int lane = threadIdx.x & 63;
  const int wv = threadIdx.x >> 6;
  const int px16 = lane & 15;
  const int pxblk = tile * 4 + wv;
  const int pxl = pxblk * 16 + px16;

#pragma unroll
  for (int mt = 0; mt < 5; ++mt) {
#pragma unroll
    for (int j = 0; j < 4; ++j) {
      const int row80 = mt * 16 + (lane >> 4) * 4 + j;
      const int r = (row80 >> 4) * 32 + b * 16 + (row80 & 15);
      const float x =
          0.001f * (float)((threadIdx.x * 37 + mt * 11 + j * 5) & 255) - 0.1f;
      const float mp = 1.f / (1.f + __expf(-x));
      const float tv = mask_targets[(size_t)r * kHW + pxl];
      float av = mp * tv;
      float bv = mp * mp;
      float cv = tv;
#pragma unroll
      for (int m = 1; m <= 8; m <<= 1) {
        av += __shfl_xor(av, m, 64);
        bv += __shfl_xor(bv, m, 64);
        cv += __shfl_xor(cv, m, 64);
      }
      if (px16 == 0) {
        bred[wv][row80] = av;
        bred[wv][80 + row80] = bv;
        bred[wv][160 + row80] = cv;
      }
    }
  }
  __syncthreads();
  if (threadIdx.x < 240) {
    const int q = threadIdx.x / 80;
    const int row80 = threadIdx.x - q * 80;
    const int r = (row80 >> 4) * 32 + b * 16 + (row80 & 15);
    const float s = bred[0][threadIdx.x] + bred[1][threadIdx.x] +
                    bred[2][threadIdx.x] + bred[3][threadIdx.x];
    unsafeAtomicAdd(&acc[1024 + q * 160 + r], s);  // scratch, never read
  }
}

// ---------------------------------------------------------------------------
// REAL PATH: GEMM -> bf16 pred store (no reduce, no LDS, no barriers).
// ---------------------------------------------------------------------------
__global__ __launch_bounds__(256, 4) void gemm_store_kernel(
    const unsigned short* __restrict__ moT,
    const unsigned short* __restrict__ kbf,
    unsigned short* __restrict__ predw) {
  const int bid = blockIdx.x;
  const int b = bid / 576;
  const int tile = bid - b * 576;
  const int lane = threadIdx.x & 63;
  const int wv = threadIdx.x >> 6;
  const int px16 = lane & 15;
  const int hi8 = (lane >> 4) * 8;
  const int pxblk = tile * 4 + wv;
  const int pxl = pxblk * 16 + px16;

  const unsigned short* __restrict__ bsrc =
      moT + ((size_t)(b * 2304 + pxblk) * 8) * 512 + (size_t)lane * 8;
  bf16x8 bfr[8];
#pragma unroll
  for (int ks = 0; ks < 8; ++ks)
    bfr[ks] = *(const bf16x8*)(bsrc + (size_t)ks * 512);

  const unsigned short* __restrict__ ka =
      kbf + ((size_t)b * 80 + px16) * 256 + hi8;

  f32x4 a5[5];
#pragma unroll
  for (int mt = 0; mt < 5; ++mt) a5[mt] = (f32x4){0.f, 0.f, 0.f, 0.f};

#pragma unroll
  for (int ks = 0; ks < 8; ++ks) {
#pragma unroll
    for (int mt = 0; mt < 5; ++mt) {
      const bf16x8 af = *(const bf16x8*)(ka + mt * 4096 + ks * 32);
      a5[mt] = __builtin_amdgcn_mfma_f32_16x16x32_bf16(af, bfr[ks], a5[mt],
                                                       0, 0, 0);
    }
  }

  // D layout (m89): col = lane&15 (pixel), row80 = mt*16 + (lane>>4)*4 + reg.
  // Global flat row r = (row80>>4)*32 + b*16 + (row80&15).
#pragma unroll
  for (int mt = 0; mt < 5; ++mt) {
#pragma unroll
    for (int j = 0; j < 4; ++j) {
      const int row80 = mt * 16 + (lane >> 4) * 4 + j;
      const int r = (row80 >> 4) * 32 + b * 16 + (row80 & 15);
      predw[(size_t)r * kHW + pxl] = f2bf(a5[mt][j]);
    }
  }
}

// ---------------------------------------------------------------------------
// Dice reduction: streaming, fully contiguous. 160 rows x 18 col-blocks.
// ---------------------------------------------------------------------------
__global__ __launch_bounds__(256) void dice_kernel(
    const unsigned short* __restrict__ predw,
    const float* __restrict__ mtg, float* __restrict__ acc) {
  const int r = blockIdx.x / 18;
  const int cb = blockIdx.x - r * 18;
  const int px = cb * 2048 + threadIdx.x * 8;
  const size_t base = (size_t)r * kHW + px;
  const bf16x8 p8 = *(const bf16x8*)&predw[base];
  const float4 t0 = *(const float4*)&mtg[base];
  const float4 t1 = *(const float4*)&mtg[base + 4];
  const float tv[8] = {t0.x, t0.y, t0.z, t0.w, t1.x, t1.y, t1.z, t1.w};
  float av = 0.f, bv = 0.f, cv = 0.f;
#pragma unroll
  for (int j = 0; j < 8; ++j) {
    const float x = bf2f((unsigned short)p8[j]);
    const float mp = 1.f / (1.f + __expf(-x));
    av = fmaf(mp, tv[j], av);
    bv = fmaf(mp, mp, bv);
    cv += tv[j];  // binary targets: t*t == t
  }
  av = wave_sum(av);
  bv = wave_sum(bv);
  cv = wave_sum(cv);
  __shared__ float st[12];
  const int w = threadIdx.x >> 6;
  if ((threadIdx.x & 63) == 0) {
    st[w] = av;
    st[4 + w] = bv;
    st[8 + w] = cv;
  }
  __syncthreads();
  if (threadIdx.x < 3) {
    const int q = threadIdx.x;
    unsafeAtomicAdd(&acc[q * 160 + r], st[q * 4] + st[q * 4 + 1] +
                                           st[q * 4 + 2] + st[q * 4 + 3]);
  }
}

// ---------------------------------------------------------------------------
// Focal loss. One (cell, class-quad) per thread; 605 blocks x 256.
// ---------------------------------------------------------------------------
__global__ __launch_bounds__(256) void focal_kernel(
    const float* __restrict__ c0, const float* __restrict__ c1,
    const float* __restrict__ c2, const float* __restrict__ c3,
    const float* __restrict__ c4,
    const int* __restrict__ t0, const int* __restrict__ t1,
    const int* __restrict__ t2, const int* __restrict__ t3,
    const int* __restrict__ t4,
    float* __restrict__ acc) {
  const int idx = blockIdx.x * 256 + threadIdx.x;  // < 154880 exactly
  const int n = idx / 20;
  const int cq = (idx - n * 20) * 4;
  int t;
  const float* crow;
  if (n < 3200) {
    t = t0[n]; crow = c0 + (size_t)n * 80;
  } else if (n < 5792) {
    const int o = n - 3200; t = t1[o]; crow = c1 + (size_t)o * 80;
  } else if (n < 6944) {
    const int o = n - 5792; t = t2[o]; crow = c2 + (size_t)o * 80;
  } else if (n < 7456) {
    const int o = n - 6944; t = t3[o]; crow = c3 + (size_t)o * 80;
  } else {
    const int o = n - 7456; t = t4[o]; crow = c4 + (size_t)o * 80;
  }
  float term = 0.f, np = 0.f;
  if (t > -1) {
    const float4 pv4 = *(const float4*)&crow[cq];
    const float pvs[4] = {pv4.x, pv4.y, pv4.z, pv4.w};
#pragma unroll
    for (int j = 0; j < 4; ++j) {
      float pv = fminf(fmaxf(pvs[j], 1e-4f), 1.f - 1e-4f);
      const bool gm = (cq + j == t);
      const float af = gm ? 0.25f : 0.75f;
      const float pt = gm ? pv : 1.f - pv;
      const float om = 1.f - pt;
      term = fmaf(af * om * om, -__logf(pt), term);
    }
    if (cq == 0) np = 1.f;
  }
  term = wave_sum(term);
  np = wave_sum(np);
  __shared__ float st[8];
  const int wid = threadIdx.x >> 6;
  if ((threadIdx.x & 63) == 0) {
    st[wid] = term;
    st[4 + wid] = np;
  }
  __syncthreads();
  if (threadIdx.x == 0) {
    unsafeAtomicAdd(&acc[480], st[0] + st[1] + st[2] + st[3]);
    unsafeAtomicAdd(&acc[481], st[4] + st[5] + st[6] + st[7]);
  }
}

__global__ __launch_bounds__(64) void finalize_kernel(
    const float* __restrict__ acc, float* __restrict__ out) {
  const int tid = threadIdx.x;
  float s = 0.f;
#pragma unroll
  for (int rr = 0; rr < 3; ++rr) {
    const int r = tid + rr * 64;
    if (r < 160) {
      const float a = acc[r];
      const float bb = acc[160 + r];
      const float cc = acc[320 + r];
      s += 1.f - 2.f * a / (bb + cc + 1e-4f);
    }
  }
  s = wave_sum(s);
  if (tid == 0) {
    out[0] = 3.0f * (s / 160.f);   // MASK_W * mask_loss
    out[1] = acc[480] / acc[481];  // CLS_W * cls_loss
  }
}

}  // namespace

extern "C" void kernel_launch(void* const* d_in, const int* in_sizes, int n_in,
                              void* d_out, int out_size, void* d_ws,
                              size_t ws_size, hipStream_t stream) {
  const float* mask_out = (const float*)d_in[0];
  const float* k[5];
  const float* cc[5];
  const int* pp[5];
  const int* tt[5];
  for (int i = 0; i < 5; ++i) {
    k[i] = (const float*)d_in[1 + 4 * i];
    cc[i] = (const float*)d_in[2 + 4 * i];
    pp[i] = (const int*)d_in[3 + 4 * i];
    tt[i] = (const int*)d_in[4 + 4 * i];
  }
  const float* mt = (const float*)d_in[21];

  char* ws = (char*)d_ws;
  float* acc = (float*)ws;                                 // 2048 f @ 0
  unsigned short* kbf = (unsigned short*)(ws + 8192);      // 81,920 B
  unsigned short* moT = (unsigned short*)(ws + 90112);     // 37,748,736 B
  unsigned short* predw = (unsigned short*)(ws + 37838848);  // 11,796,480 B
  float* out = (float*)d_out;

  hipLaunchKernelGGL(repack_prep_kernel, dim3(kRepackBlocks + 161), dim3(256),
                     0, stream, mask_out, k[0], k[1], k[2], k[3], k[4], pp[0],
                     pp[1], pp[2], pp[3], pp[4], moT, kbf, acc);
  // --- diagnostics (attribution via rocprof; outputs unused) ---
  hipLaunchKernelGGL(gemm_only_diag, dim3(kGemmBlocks), dim3(256), 0, stream,
                     moT, kbf);
  hipLaunchKernelGGL(epi_only_diag, dim3(kGemmBlocks), dim3(256), 0, stream,
                     mt, acc);
  // --- real path ---
  hipLaunchKernelGGL(gemm_store_kernel, dim3(kGemmBlocks), dim3(256), 0,
                     stream, moT, kbf, predw);
  hipLaunchKernelGGL(dice_kernel, dim3(160 * 18), dim3(256), 0, stream, predw,
                     mt, acc);
  hipLaunchKernelGGL(focal_kernel, dim3(605), dim3(256), 0, stream, cc[0],
                     cc[1], cc[2], cc[3], cc[4], tt[0], tt[1], tt[2], tt[3],
                     tt[4], acc);
  hipLaunchKernelGGL(finalize_kernel, dim3(1), dim3(64), 0, stream, acc, out);
}

// Round 12
// 74.552 us; speedup vs baseline: 1.8023x; 1.8023x over previous
//
#include <hip/hip_runtime.h>
#include <hip/hip_bf16.h>

namespace {

constexpr int kHW = 36864;  // 192*192

typedef __attribute__((ext_vector_type(8))) short bf16x8;
typedef __attribute__((ext_vector_type(4))) float f32x4;

__device__ __forceinline__ unsigned short f2bf(float x) {
  return __builtin_bit_cast(unsigned short, __float2bfloat16(x));
}
__device__ __forceinline__ float bf2f(unsigned short u) {
  return __builtin_bit_cast(float, (unsigned int)u << 16);
}

__device__ __forceinline__ float wave_sum(float v) {
#pragma unroll
  for (int off = 32; off; off >>= 1) v += __shfl_xor(v, off, 64);
  return v;
}

// ---------------------------------------------------------------------------
// Prep: block 0 zeroes acc; blocks 1..160 gather one positive kernel row each
// into dense bf16 kbf[b][row80][256].
// ---------------------------------------------------------------------------
__global__ __launch_bounds__(256) void prep_kernel(
    const float* __restrict__ k0, const float* __restrict__ k1,
    const float* __restrict__ k2, const float* __restrict__ k3,
    const float* __restrict__ k4,
    const int* __restrict__ q0, const int* __restrict__ q1,
    const int* __restrict__ q2, const int* __restrict__ q3,
    const int* __restrict__ q4,
    unsigned short* __restrict__ kbf, float* __restrict__ acc) {
  const int bid = blockIdx.x;
  if (bid == 0) {
    for (int i = threadIdx.x; i < 482; i += 256) acc[i] = 0.f;
    return;
  }
  const int idx = bid - 1;  // 0..159
  const int b = idx / 80;
  const int row = idx - b * 80;
  if (threadIdx.x >= 128) return;
  const int l = row >> 4, p = row & 15;
  const float* kb[5] = {k0, k1, k2, k3, k4};
  const int* pb[5] = {q0, q1, q2, q3, q4};
  const int bg2[5] = {b * 1600, b * 1296, b * 576, b * 256, b * 144};
  const int pos = pb[l][b * 16 + p];
  const int ch = threadIdx.x * 2;
  const float2 kv = *(const float2*)(kb[l] + (size_t)(bg2[l] + pos) * 256 + ch);
  *(unsigned int*)&kbf[((size_t)b * 80 + row) * 256 + ch] =
      (unsigned int)f2bf(kv.x) | ((unsigned int)f2bf(kv.y) << 16);
}

// ---------------------------------------------------------------------------
// GEMM kernel, allocator-fixed. Block = 256 thr (4 waves), 64 px x 80 rows;
// grid = 1152. Each lane loads ALL 64 B-floats (8 ks x 8 ch, strided f32
// direct from mask_out) into named registers, asm-pins them so the register
// allocator CANNOT sink the loads into serial load->wait->use chains (the
// R5-R10 pathology: VGPR squeezed to 32-52, pipeline serialized). One
// waitcnt covers 64 in-flight loads/lane. Then cvt->bf16 and 40 MFMAs
// (A-frags from L1-hot kbf; A is identical across the wave's 4 px-groups).
// Epilogue: plain bf16 pred store (dice reduction runs as a separate
// streaming kernel -> no contended atomics here).
// ---------------------------------------------------------------------------
__global__ __attribute__((amdgpu_flat_work_group_size(256, 256),
                          amdgpu_waves_per_eu(2, 4)))
void gemm_store_kernel(const float* __restrict__ mask_out,
                       const unsigned short* __restrict__ kbf,
                       unsigned short* __restrict__ predw) {
  const int bid = blockIdx.x;
  const int b = bid / 576;
  const int tile = bid - b * 576;
  const int px0 = tile * 64;
  const int lane = threadIdx.x & 63;
  const int wv = threadIdx.x >> 6;
  const int px16 = lane & 15;
  const int hi8 = (lane >> 4) * 8;
  const int pxl = px0 + wv * 16 + px16;

  const float* __restrict__ mo =
      mask_out + (size_t)b * 256 * kHW + (size_t)hi8 * kHW + pxl;

  // ---- issue all 64 B-loads (independent, deep in-flight queue) ----
  float br[8][8];
#pragma unroll
  for (int ks = 0; ks < 8; ++ks)
#pragma unroll
    for (int j = 0; j < 8; ++j)
      br[ks][j] = mo[(size_t)(ks * 32 + j) * kHW];

  // ---- pin: forces all 64 values materialized in VGPRs here ----
#pragma unroll
  for (int ks = 0; ks < 8; ++ks)
#pragma unroll
    for (int j = 0; j < 8; ++j) asm volatile("" : "+v"(br[ks][j]));

  const unsigned short* __restrict__ ka =
      kbf + ((size_t)b * 80 + px16) * 256 + hi8;

  f32x4 a5[5];
#pragma unroll
  for (int mt = 0; mt < 5; ++mt) a5[mt] = (f32x4){0.f, 0.f, 0.f, 0.f};

#pragma unroll
  for (int ks = 0; ks < 8; ++ks) {
    bf16x8 bb;
#pragma unroll
    for (int j = 0; j < 8; ++j) bb[j] = (short)f2bf(br[ks][j]);
#pragma unroll
    for (int mt = 0; mt < 5; ++mt) {
      const bf16x8 af = *(const bf16x8*)(ka + mt * 4096 + ks * 32);
      a5[mt] =
          __builtin_amdgcn_mfma_f32_16x16x32_bf16(af, bb, a5[mt], 0, 0, 0);
    }
  }

  // D layout (m89): col = lane&15 (pixel), row80 = mt*16 + (lane>>4)*4 + reg.
  // Global flat row r = (row80>>4)*32 + b*16 + (row80&15).
#pragma unroll
  for (int mt = 0; mt < 5; ++mt) {
#pragma unroll
    for (int j = 0; j < 4; ++j) {
      const int row80 = mt * 16 + (lane >> 4) * 4 + j;
      const int r = (row80 >> 4) * 32 + b * 16 + (row80 & 15);
      predw[(size_t)r * kHW + pxl] = f2bf(a5[mt][j]);
    }
  }
}

// ---------------------------------------------------------------------------
// Dice reduction: streaming, fully contiguous. 160 rows x 18 col-blocks.
// ---------------------------------------------------------------------------
__global__ __launch_bounds__(256) void dice_kernel(
    const unsigned short* __restrict__ predw,
    const float* __restrict__ mtg, float* __restrict__ acc) {
  const int r = blockIdx.x / 18;
  const int cb = blockIdx.x - r * 18;
  const int px = cb * 2048 + threadIdx.x * 8;
  const size_t base = (size_t)r * kHW + px;
  const bf16x8 p8 = *(const bf16x8*)&predw[base];
  const float4 t0 = *(const float4*)&mtg[base];
  const float4 t1 = *(const float4*)&mtg[base + 4];
  const float tv[8] = {t0.x, t0.y, t0.z, t0.w, t1.x, t1.y, t1.z, t1.w};
  float av = 0.f, bv = 0.f, cv = 0.f;
#pragma unroll
  for (int j = 0; j < 8; ++j) {
    const float x = bf2f((unsigned short)p8[j]);
    const float mp = 1.f / (1.f + __expf(-x));
    av = fmaf(mp, tv[j], av);
    bv = fmaf(mp, mp, bv);
    cv += tv[j];  // binary targets: t*t == t
  }
  av = wave_sum(av);
  bv = wave_sum(bv);
  cv = wave_sum(cv);
  __shared__ float st[12];
  const int w = threadIdx.x >> 6;
  if ((threadIdx.x & 63) == 0) {
    st[w] = av;
    st[4 + w] = bv;
    st[8 + w] = cv;
  }
  __syncthreads();
  if (threadIdx.x < 3) {
    const int q = threadIdx.x;
    unsafeAtomicAdd(&acc[q * 160 + r], st[q * 4] + st[q * 4 + 1] +
                                           st[q * 4 + 2] + st[q * 4 + 3]);
  }
}

// ---------------------------------------------------------------------------
// Focal loss. One (cell, class-quad) per thread; 605 blocks x 256.
// ---------------------------------------------------------------------------
__global__ __launch_bounds__(256) void focal_kernel(
    const float* __restrict__ c0, const float* __restrict__ c1,
    const float* __restrict__ c2, const float* __restrict__ c3,
    const float* __restrict__ c4,
    const int* __restrict__ t0, const int* __restrict__ t1,
    const int* __restrict__ t2, const int* __restrict__ t3,
    const int* __restrict__ t4,
    float* __restrict__ acc) {
  const int idx = blockIdx.x * 256 + threadIdx.x;  // < 154880 exactly
  const int n = idx / 20;
  const int cq = (idx - n * 20) * 4;
  int t;
  const float* crow;
  if (n < 3200) {
    t = t0[n]; crow = c0 + (size_t)n * 80;
  } else if (n < 5792) {
    const int o = n - 3200; t = t1[o]; crow = c1 + (size_t)o * 80;
  } else if (n < 6944) {
    const int o = n - 5792; t = t2[o]; crow = c2 + (size_t)o * 80;
  } else if (n < 7456) {
    const int o = n - 6944; t = t3[o]; crow = c3 + (size_t)o * 80;
  } else {
    const int o = n - 7456; t = t4[o]; crow = c4 + (size_t)o * 80;
  }
  float term = 0.f, np = 0.f;
  if (t > -1) {
    const float4 pv4 = *(const float4*)&crow[cq];
    const float pvs[4] = {pv4.x, pv4.y, pv4.z, pv4.w};
#pragma unroll
    for (int j = 0; j < 4; ++j) {
      float pv = fminf(fmaxf(pvs[j], 1e-4f), 1.f - 1e-4f);
      const bool gm = (cq + j == t);
      const float af = gm ? 0.25f : 0.75f;
      const float pt = gm ? pv : 1.f - pv;
      const float om = 1.f - pt;
      term = fmaf(af * om * om, -__logf(pt), term);
    }
    if (cq == 0) np = 1.f;
  }
  term = wave_sum(term);
  np = wave_sum(np);
  __shared__ float st[8];
  const int wid = threadIdx.x >> 6;
  if ((threadIdx.x & 63) == 0) {
    st[wid] = term;
    st[4 + wid] = np;
  }
  __syncthreads();
  if (threadIdx.x == 0) {
    unsafeAtomicAdd(&acc[480], st[0] + st[1] + st[2] + st[3]);
    unsafeAtomicAdd(&acc[481], st[4] + st[5] + st[6] + st[7]);
  }
}

__global__ __launch_bounds__(64) void finalize_kernel(
    const float* __restrict__ acc, float* __restrict__ out) {
  const int tid = threadIdx.x;
  float s = 0.f;
#pragma unroll
  for (int rr = 0; rr < 3; ++rr) {
    const int r = tid + rr * 64;
    if (r < 160) {
      const float a = acc[r];
      const float bb = acc[160 + r];
      const float cc = acc[320 + r];
      s += 1.f - 2.f * a / (bb + cc + 1e-4f);
    }
  }
  s = wave_sum(s);
  if (tid == 0) {
    out[0] = 3.0f * (s / 160.f);   // MASK_W * mask_loss
    out[1] = acc[480] / acc[481];  // CLS_W * cls_loss
  }
}

}  // namespace

extern "C" void kernel_launch(void* const* d_in, const int* in_sizes, int n_in,
                              void* d_out, int out_size, void* d_ws,
                              size_t ws_size, hipStream_t stream) {
  const float* mask_out = (const float*)d_in[0];
  const float* k[5];
  const float* cc[5];
  const int* pp[5];
  const int* tt[5];
  for (int i = 0; i < 5; ++i) {
    k[i] = (const float*)d_in[1 + 4 * i];
    cc[i] = (const float*)d_in[2 + 4 * i];
    pp[i] = (const int*)d_in[3 + 4 * i];
    tt[i] = (const int*)d_in[4 + 4 * i];
  }
  const float* mt = (const float*)d_in[21];

  char* ws = (char*)d_ws;
  float* acc = (float*)ws;                                // 2048 f @ 0
  unsigned short* kbf = (unsigned short*)(ws + 8192);     // 81,920 B
  unsigned short* predw = (unsigned short*)(ws + 90112);  // 11,796,480 B
  float* out = (float*)d_out;

  hipLaunchKernelGGL(prep_kernel, dim3(161), dim3(256), 0, stream, k[0], k[1],
                     k[2], k[3], k[4], pp[0], pp[1], pp[2], pp[3], pp[4], kbf,
                     acc);
  hipLaunchKernelGGL(gemm_store_kernel, dim3(1152), dim3(256), 0, stream,
                     mask_out, kbf, predw);
  hipLaunchKernelGGL(dice_kernel, dim3(160 * 18), dim3(256), 0, stream, predw,
                     mt, acc);
  hipLaunchKernelGGL(focal_kernel, dim3(605), dim3(256), 0, stream, cc[0],
                     cc[1], cc[2], cc[3], cc[4], tt[0], tt[1], tt[2], tt[3],
                     tt[4], acc);
  hipLaunchKernelGGL(finalize_kernel, dim3(1), dim3(64), 0, stream, acc, out);
}

// Round 13
// 72.453 us; speedup vs baseline: 1.8545x; 1.0290x over previous
//
#include <hip/hip_runtime.h>
#include <hip/hip_bf16.h>

namespace {

constexpr int kHW = 36864;  // 192*192
constexpr int kDiceBlocks = 2880;  // 160 rows x 18 col-blocks
constexpr int kFocalBlocks = 605;  // 7744 cells x 20 quads / 256

typedef __attribute__((ext_vector_type(8))) short bf16x8;
typedef __attribute__((ext_vector_type(4))) float f32x4;

__device__ __forceinline__ unsigned short f2bf(float x) {
  return __builtin_bit_cast(unsigned short, __float2bfloat16(x));
}
__device__ __forceinline__ float bf2f(unsigned short u) {
  return __builtin_bit_cast(float, (unsigned int)u << 16);
}

__device__ __forceinline__ float wave_sum(float v) {
#pragma unroll
  for (int off = 32; off; off >>= 1) v += __shfl_xor(v, off, 64);
  return v;
}

// ---------------------------------------------------------------------------
// Prep: block 0 zeroes acc; blocks 1..160 gather one positive kernel row each
// into dense bf16 kbf[b][row80][256].
// ---------------------------------------------------------------------------
__global__ __launch_bounds__(256) void prep_kernel(
    const float* __restrict__ k0, const float* __restrict__ k1,
    const float* __restrict__ k2, const float* __restrict__ k3,
    const float* __restrict__ k4,
    const int* __restrict__ q0, const int* __restrict__ q1,
    const int* __restrict__ q2, const int* __restrict__ q3,
    const int* __restrict__ q4,
    unsigned short* __restrict__ kbf, float* __restrict__ acc) {
  const int bid = blockIdx.x;
  if (bid == 0) {
    for (int i = threadIdx.x; i < 482; i += 256) acc[i] = 0.f;
    return;
  }
  const int idx = bid - 1;  // 0..159
  const int b = idx / 80;
  const int row = idx - b * 80;
  if (threadIdx.x >= 128) return;
  const int l = row >> 4, p = row & 15;
  const float* kb[5] = {k0, k1, k2, k3, k4};
  const int* pb[5] = {q0, q1, q2, q3, q4};
  const int bg2[5] = {b * 1600, b * 1296, b * 576, b * 256, b * 144};
  const int pos = pb[l][b * 16 + p];
  const int ch = threadIdx.x * 2;
  const float2 kv = *(const float2*)(kb[l] + (size_t)(bg2[l] + pos) * 256 + ch);
  *(unsigned int*)&kbf[((size_t)b * 80 + row) * 256 + ch] =
      (unsigned int)f2bf(kv.x) | ((unsigned int)f2bf(kv.y) << 16);
}

// ---------------------------------------------------------------------------
// GEMM kernel, single-barrier full-tile staging (the m97-proven pattern).
// Block = 256 thr (4 waves), 64 px x 80 rows; grid = 1152. Each thread issues
// 16 back-to-back global_load_lds (width=16, NO destination VGPRs -> the
// register allocator cannot serialize them) staging the block's whole
// [256 ch][64 px] f32 B-tile (64 KB LDS); ONE vmcnt drain at the barrier with
// 4 KB/thread-quad in flight. Compute: per ks, 8 ds_read_b32 per lane (4-way
// bank alias = 1.58x, acceptable), cvt->bf16, 5 MFMAs; A-frags gathered from
// L1/L2-hot kbf. Epilogue: plain bf16 pred store (dice runs separately).
// ---------------------------------------------------------------------------
__global__ __launch_bounds__(256, 2) void gemm_store_kernel(
    const float* __restrict__ mask_out,
    const unsigned short* __restrict__ kbf,
    unsigned short* __restrict__ predw) {
  __shared__ float bufB[256][64];  // 64 KB: [ch][px]

  const int bid = blockIdx.x;
  const int b = bid / 576;
  const int tile = bid - b * 576;
  const int px0 = tile * 64;
  const int lane = threadIdx.x & 63;
  const int wv = threadIdx.x >> 6;
  const int px16 = lane & 15;
  const int hi8 = (lane >> 4) * 8;
  const int pxl = px0 + wv * 16 + px16;

  // Staging: thread quad covers ch = i*16 + wv*4 + (lane>>4), px = (lane&15)*4.
  // One instruction fills 4 consecutive ch rows (1 KB).
  const float* __restrict__ gstage = mask_out + (size_t)b * 256 * kHW +
                                     (size_t)(wv * 4 + (lane >> 4)) * kHW +
                                     px0 + (lane & 15) * 4;
#pragma unroll
  for (int i = 0; i < 16; ++i) {
    __builtin_amdgcn_global_load_lds(
        (const __attribute__((address_space(1))) unsigned int*)(gstage +
                                                                (size_t)i * 16 *
                                                                    kHW),
        (__attribute__((address_space(3))) unsigned int*)&bufB[i * 16 + wv * 4]
            [0],
        16, 0, 0);
  }
  __syncthreads();  // single vmcnt(0) drain; 16 KB/wave was in flight

  const unsigned short* __restrict__ ka =
      kbf + ((size_t)b * 80 + px16) * 256 + hi8;

  f32x4 a5[5];
#pragma unroll
  for (int mt = 0; mt < 5; ++mt) a5[mt] = (f32x4){0.f, 0.f, 0.f, 0.f};

#pragma unroll
  for (int ks = 0; ks < 8; ++ks) {
    float fb[8];
#pragma unroll
    for (int j = 0; j < 8; ++j) fb[j] = bufB[ks * 32 + hi8 + j][wv * 16 + px16];
    bf16x8 bb;
#pragma unroll
    for (int j = 0; j < 8; ++j) bb[j] = (short)f2bf(fb[j]);
#pragma unroll
    for (int mt = 0; mt < 5; ++mt) {
      const bf16x8 af = *(const bf16x8*)(ka + mt * 4096 + ks * 32);
      a5[mt] =
          __builtin_amdgcn_mfma_f32_16x16x32_bf16(af, bb, a5[mt], 0, 0, 0);
    }
  }

  // D layout (m89): col = lane&15 (pixel), row80 = mt*16 + (lane>>4)*4 + reg.
  // Global flat row r = (row80>>4)*32 + b*16 + (row80&15).
#pragma unroll
  for (int mt = 0; mt < 5; ++mt) {
#pragma unroll
    for (int j = 0; j < 4; ++j) {
      const int row80 = mt * 16 + (lane >> 4) * 4 + j;
      const int r = (row80 >> 4) * 32 + b * 16 + (row80 & 15);
      predw[(size_t)r * kHW + pxl] = f2bf(a5[mt][j]);
    }
  }
}

// ---------------------------------------------------------------------------
// Dice (blocks < 2880) + focal (tail). Dice: streaming contiguous bf16x8
// pred + float4 targets, wave reduce, 3 atomics/block. Focal: one
// (cell, class-quad) per thread.
// ---------------------------------------------------------------------------
__global__ __launch_bounds__(256) void dice_focal_kernel(
    const unsigned short* __restrict__ predw, const float* __restrict__ mtg,
    const float* __restrict__ c0, const float* __restrict__ c1,
    const float* __restrict__ c2, const float* __restrict__ c3,
    const float* __restrict__ c4,
    const int* __restrict__ t0, const int* __restrict__ t1,
    const int* __restrict__ t2, const int* __restrict__ t3,
    const int* __restrict__ t4,
    float* __restrict__ acc) {
  const int bid = blockIdx.x;
  __shared__ float st[12];

  if (bid < kDiceBlocks) {
    const int r = bid / 18;
    const int cb = bid - r * 18;
    const int px = cb * 2048 + threadIdx.x * 8;
    const size_t base = (size_t)r * kHW + px;
    const bf16x8 p8 = *(const bf16x8*)&predw[base];
    const float4 u0 = *(const float4*)&mtg[base];
    const float4 u1 = *(const float4*)&mtg[base + 4];
    const float tv[8] = {u0.x, u0.y, u0.z, u0.w, u1.x, u1.y, u1.z, u1.w};
    float av = 0.f, bv = 0.f, cv = 0.f;
#pragma unroll
    for (int j = 0; j < 8; ++j) {
      const float x = bf2f((unsigned short)p8[j]);
      const float mp = 1.f / (1.f + __expf(-x));
      av = fmaf(mp, tv[j], av);
      bv = fmaf(mp, mp, bv);
      cv += tv[j];  // binary targets: t*t == t
    }
    av = wave_sum(av);
    bv = wave_sum(bv);
    cv = wave_sum(cv);
    const int w = threadIdx.x >> 6;
    if ((threadIdx.x & 63) == 0) {
      st[w] = av;
      st[4 + w] = bv;
      st[8 + w] = cv;
    }
    __syncthreads();
    if (threadIdx.x < 3) {
      const int q = threadIdx.x;
      unsafeAtomicAdd(&acc[q * 160 + r], st[q * 4] + st[q * 4 + 1] +
                                             st[q * 4 + 2] + st[q * 4 + 3]);
    }
    return;
  }

  // ---------------- focal tail ----------------
  const int idx = (bid - kDiceBlocks) * 256 + threadIdx.x;  // < 154880
  const int n = idx / 20;
  const int cq = (idx - n * 20) * 4;
  int t;
  const float* crow;
  if (n < 3200) {
    t = t0[n]; crow = c0 + (size_t)n * 80;
  } else if (n < 5792) {
    const int o = n - 3200; t = t1[o]; crow = c1 + (size_t)o * 80;
  } else if (n < 6944) {
    const int o = n - 5792; t = t2[o]; crow = c2 + (size_t)o * 80;
  } else if (n < 7456) {
    const int o = n - 6944; t = t3[o]; crow = c3 + (size_t)o * 80;
  } else {
    const int o = n - 7456; t = t4[o]; crow = c4 + (size_t)o * 80;
  }
  float term = 0.f, np = 0.f;
  if (t > -1) {
    const float4 pv4 = *(const float4*)&crow[cq];
    const float pvs[4] = {pv4.x, pv4.y, pv4.z, pv4.w};
#pragma unroll
    for (int j = 0; j < 4; ++j) {
      float pv = fminf(fmaxf(pvs[j], 1e-4f), 1.f - 1e-4f);
      const bool gm = (cq + j == t);
      const float af = gm ? 0.25f : 0.75f;
      const float pt = gm ? pv : 1.f - pv;
      const float om = 1.f - pt;
      term = fmaf(af * om * om, -__logf(pt), term);
    }
    if (cq == 0) np = 1.f;
  }
  term = wave_sum(term);
  np = wave_sum(np);
  const int wid = threadIdx.x >> 6;
  if ((threadIdx.x & 63) == 0) {
    st[wid] = term;
    st[4 + wid] = np;
  }
  __syncthreads();
  if (threadIdx.x == 0) {
    unsafeAtomicAdd(&acc[480], st[0] + st[1] + st[2] + st[3]);
    unsafeAtomicAdd(&acc[481], st[4] + st[5] + st[6] + st[7]);
  }
}

__global__ __launch_bounds__(64) void finalize_kernel(
    const float* __restrict__ acc, float* __restrict__ out) {
  const int tid = threadIdx.x;
  float s = 0.f;
#pragma unroll
  for (int rr = 0; rr < 3; ++rr) {
    const int r = tid + rr * 64;
    if (r < 160) {
      const float a = acc[r];
      const float bb = acc[160 + r];
      const float cc = acc[320 + r];
      s += 1.f - 2.f * a / (bb + cc + 1e-4f);
    }
  }
  s = wave_sum(s);
  if (tid == 0) {
    out[0] = 3.0f * (s / 160.f);   // MASK_W * mask_loss
    out[1] = acc[480] / acc[481];  // CLS_W * cls_loss
  }
}

}  // namespace

extern "C" void kernel_launch(void* const* d_in, const int* in_sizes, int n_in,
                              void* d_out, int out_size, void* d_ws,
                              size_t ws_size, hipStream_t stream) {
  const float* mask_out = (const float*)d_in[0];
  const float* k[5];
  const float* cc[5];
  const int* pp[5];
  const int* tt[5];
  for (int i = 0; i < 5; ++i) {
    k[i] = (const float*)d_in[1 + 4 * i];
    cc[i] = (const float*)d_in[2 + 4 * i];
    pp[i] = (const int*)d_in[3 + 4 * i];
    tt[i] = (const int*)d_in[4 + 4 * i];
  }
  const float* mt = (const float*)d_in[21];

  char* ws = (char*)d_ws;
  float* acc = (float*)ws;                                // 2048 f @ 0
  unsigned short* kbf = (unsigned short*)(ws + 8192);     // 81,920 B
  unsigned short* predw = (unsigned short*)(ws + 90112);  // 11,796,480 B
  float* out = (float*)d_out;

  hipLaunchKernelGGL(prep_kernel, dim3(161), dim3(256), 0, stream, k[0], k[1],
                     k[2], k[3], k[4], pp[0], pp[1], pp[2], pp[3], pp[4], kbf,
                     acc);
  hipLaunchKernelGGL(gemm_store_kernel, dim3(1152), dim3(256), 0, stream,
                     mask_out, kbf, predw);
  hipLaunchKernelGGL(dice_focal_kernel, dim3(kDiceBlocks + kFocalBlocks),
                     dim3(256), 0, stream, predw, mt, cc[0], cc[1], cc[2],
                     cc[3], cc[4], tt[0], tt[1], tt[2], tt[3], tt[4], acc);
  hipLaunchKernelGGL(finalize_kernel, dim3(1), dim3(64), 0, stream, acc, out);
}